// Round 2
// baseline (2588.277 us; speedup 1.0000x reference)
//
#include <hip/hip_runtime.h>

// VQ: B=200000 rows of D=128 fp32; K=1024 codebook rows.
// Output: quant_x [B*D] fp32, then codes [B] written as fp32 values.
//
// Strategy: lane = row. x row held entirely in VGPRs (128 regs). Codebook
// address is wave-uniform -> compiler emits scalar s_load through the
// constant cache, so the inner loop is pure v_fma_f32 with SGPR operand.
// R0 lesson: default launch_bounds let the compiler cap at 80 VGPRs and
// spill xr[128] -> 84% stall. Grid is only ~3 blocks/CU (12 waves/CU), so
// allocating ~160 VGPRs is free. __launch_bounds__(256,2) caps at 256.

#define DDIM 128
#define KCODES 1024

__global__ void csq_kernel(const float* __restrict__ cb, float* __restrict__ csq) {
    int k = blockIdx.x * blockDim.x + threadIdx.x;
    if (k >= KCODES) return;
    const float* __restrict__ c = cb + (long)k * DDIM;
    float s0 = 0.f, s1 = 0.f, s2 = 0.f, s3 = 0.f;
#pragma unroll
    for (int d = 0; d < DDIM; d += 4) {
        s0 = fmaf(c[d + 0], c[d + 0], s0);
        s1 = fmaf(c[d + 1], c[d + 1], s1);
        s2 = fmaf(c[d + 2], c[d + 2], s2);
        s3 = fmaf(c[d + 3], c[d + 3], s3);
    }
    csq[k] = (s0 + s1) + (s2 + s3);
}

__launch_bounds__(256, 2)  // VGPR cap 256: xr[128]+accum+bufs ~160, spill-free
__global__ void vq_kernel(const float* __restrict__ x, const float* __restrict__ cb,
                          const float* __restrict__ csq, float* __restrict__ quant,
                          float* __restrict__ codes, int B) {
    const long row = (long)blockIdx.x * blockDim.x + threadIdx.x;
    const bool active = row < B;
    const long r = active ? row : 0;

    // Load this lane's x row into registers (32 x float4 = 128 VGPRs).
    float xr[DDIM];
    const float4* __restrict__ xp = (const float4*)(x + r * DDIM);
#pragma unroll
    for (int i = 0; i < DDIM / 4; ++i) {
        float4 v = xp[i];
        xr[4 * i + 0] = v.x;
        xr[4 * i + 1] = v.y;
        xr[4 * i + 2] = v.z;
        xr[4 * i + 3] = v.w;
    }

    // ||x||^2 with 4 partial chains (same association as R0 -> bit-exact match).
    float s0 = 0.f, s1 = 0.f, s2 = 0.f, s3 = 0.f;
#pragma unroll
    for (int d = 0; d < DDIM; d += 4) {
        s0 = fmaf(xr[d + 0], xr[d + 0], s0);
        s1 = fmaf(xr[d + 1], xr[d + 1], s1);
        s2 = fmaf(xr[d + 2], xr[d + 2], s2);
        s3 = fmaf(xr[d + 3], xr[d + 3], s3);
    }
    const float x_sq = (s0 + s1) + (s2 + s3);

    float best = 3.4e38f;
    int bidx = 0;
    // Unroll-by-2: two independent accumulator sets + two uniform code
    // pointers -> scheduler can issue k+1's s_loads under k's FMAs.
#pragma unroll 2
    for (int k = 0; k < KCODES; ++k) {
        const float* __restrict__ c = cb + (long)k * DDIM;  // wave-uniform address
        float a0 = 0.f, a1 = 0.f, a2 = 0.f, a3 = 0.f;
#pragma unroll
        for (int d = 0; d < DDIM; d += 4) {
            a0 = fmaf(xr[d + 0], c[d + 0], a0);
            a1 = fmaf(xr[d + 1], c[d + 1], a1);
            a2 = fmaf(xr[d + 2], c[d + 2], a2);
            a3 = fmaf(xr[d + 3], c[d + 3], a3);
        }
        const float dot = (a0 + a1) + (a2 + a3);
        const float dist = fmaf(-2.0f, dot, x_sq) + csq[k];
        if (dist < best) { best = dist; bidx = k; }  // strict < == first-index tie-break
    }

    if (active) {
        const float4* __restrict__ cc = (const float4*)(cb + (long)bidx * DDIM);
        float4* __restrict__ qp = (float4*)(quant + row * DDIM);
#pragma unroll
        for (int i = 0; i < DDIM / 4; ++i) qp[i] = cc[i];
        codes[row] = (float)bidx;
    }
}

extern "C" void kernel_launch(void* const* d_in, const int* in_sizes, int n_in,
                              void* d_out, int out_size, void* d_ws, size_t ws_size,
                              hipStream_t stream) {
    const float* x  = (const float*)d_in[0];
    const float* cb = (const float*)d_in[1];
    const int B = in_sizes[0] / DDIM;  // 200000

    float* quant = (float*)d_out;
    float* codes = (float*)d_out + (size_t)B * DDIM;
    float* csq   = (float*)d_ws;  // 1024 floats of scratch (recomputed every launch)

    csq_kernel<<<(KCODES + 255) / 256, 256, 0, stream>>>(cb, csq);

    const int blocks = (B + 255) / 256;
    vq_kernel<<<blocks, 256, 0, stream>>>(x, cb, csq, quant, codes, B);
}

// Round 3
// 1024.904 us; speedup vs baseline: 2.5254x; 2.5254x over previous
//
#include <hip/hip_runtime.h>

// VQ: B=200000 rows (D=128 fp32) vs K=1024 codes; out = [quant B*D | codes B] fp32.
//
// R1 lesson: per-lane xr[128] never lands in VGPRs (alloc stuck at 80, 84% stall).
// -> Canonical register-tiled LDS GEMM (m93-style): block = 64 rows x 128-code
// tiles, thread = 4x8 microtile of scalars, x staged to LDS ONCE (transposed),
// fused per-row argmin epilogue. 26.2 G-MAC @ 78.6 G-FMA/s fp32 = 333 us floor.

#define DDIM 128
#define KCODES 1024
#define BM 64              // rows per block (200000 = 3125 * 64, exact)
#define BN 128             // codes per tile
#define DCH 32             // d-chunk
#define NTILES (KCODES / BN)
#define NCHUNK (DDIM / DCH)

__global__ void csq_kernel(const float* __restrict__ cb, float* __restrict__ csq) {
    int k = blockIdx.x * blockDim.x + threadIdx.x;
    if (k >= KCODES) return;
    const float* __restrict__ c = cb + (long)k * DDIM;
    float s0 = 0.f, s1 = 0.f, s2 = 0.f, s3 = 0.f;
#pragma unroll
    for (int d = 0; d < DDIM; d += 4) {
        s0 = fmaf(c[d + 0], c[d + 0], s0);
        s1 = fmaf(c[d + 1], c[d + 1], s1);
        s2 = fmaf(c[d + 2], c[d + 2], s2);
        s3 = fmaf(c[d + 3], c[d + 3], s3);
    }
    csq[k] = (s0 + s1) + (s2 + s3);
}

__launch_bounds__(256, 3)  // VGPR cap ~170; need ~90. LDS 48KB -> 3 blocks/CU.
__global__ void vq_gemm_kernel(const float* __restrict__ x, const float* __restrict__ cb,
                               const float* __restrict__ csq, float* __restrict__ quant,
                               float* __restrict__ codes) {
    __shared__ float xs[DDIM * BM];   // [d][r] transposed, 32 KB, staged once
    __shared__ float cs[DCH * BN];    // [d][k] transposed, 16 KB (reused for reduction)
    __shared__ int win[BM];

    const int tid = threadIdx.x;
    const long r0 = (long)blockIdx.x * BM;

    // ---- stage x tile (64 rows x 128 d), transposed into xs[d][r] ----
    {
        const int r = tid >> 2;            // 0..63
        const int qb = (tid & 3) * 8;      // quad base
        const float* __restrict__ xrow = x + (r0 + r) * DDIM;
#pragma unroll
        for (int j = 0; j < 8; ++j) {
            const int q = qb + j;          // quad 0..31, d = q*4
            const float4 v = *(const float4*)(xrow + q * 4);
            xs[(q * 4 + 0) * BM + r] = v.x;
            xs[(q * 4 + 1) * BM + r] = v.y;
            xs[(q * 4 + 2) * BM + r] = v.z;
            xs[(q * 4 + 3) * BM + r] = v.w;
        }
    }
    __syncthreads();

    const int tr = tid >> 4;   // 0..15 -> rows tr*4..+3
    const int tc = tid & 15;   // 0..15 -> codes {tc*4..+3} u {64+tc*4..+3}

    // ---- x_sq per row, R0's exact 4-chain (d mod 4) association ----
    float s0[4] = {0.f, 0.f, 0.f, 0.f}, s1[4] = {0.f, 0.f, 0.f, 0.f},
          s2[4] = {0.f, 0.f, 0.f, 0.f}, s3[4] = {0.f, 0.f, 0.f, 0.f};
#pragma unroll
    for (int d = 0; d < DDIM; d += 4) {
#pragma unroll
        for (int dd = 0; dd < 4; ++dd) {
            const float4 v = *(const float4*)&xs[(d + dd) * BM + tr * 4];
            float* chain = (dd == 0) ? s0 : (dd == 1) ? s1 : (dd == 2) ? s2 : s3;
            chain[0] = fmaf(v.x, v.x, chain[0]);
            chain[1] = fmaf(v.y, v.y, chain[1]);
            chain[2] = fmaf(v.z, v.z, chain[2]);
            chain[3] = fmaf(v.w, v.w, chain[3]);
        }
    }
    float xsq[4];
#pragma unroll
    for (int i = 0; i < 4; ++i) xsq[i] = (s0[i] + s1[i]) + (s2[i] + s3[i]);

    float best[4];
    int bidx[4];
#pragma unroll
    for (int i = 0; i < 4; ++i) { best[i] = 3.4e38f; bidx[i] = 0; }

    for (int ct = 0; ct < NTILES; ++ct) {
        float acc[4][8];
#pragma unroll
        for (int i = 0; i < 4; ++i)
#pragma unroll
            for (int j = 0; j < 8; ++j) acc[i][j] = 0.f;

        for (int dc = 0; dc < NCHUNK; ++dc) {
            __syncthreads();  // protect cs from previous tile's readers
            {   // stage codebook chunk: codes ct*BN+(0..127), dims dc*32..+31
                const int k = tid >> 1;           // 0..127
                const int qb = (tid & 1) * 4;     // 0 or 4
                const float* __restrict__ crow =
                    cb + (long)(ct * BN + k) * DDIM + dc * DCH;
#pragma unroll
                for (int j = 0; j < 4; ++j) {
                    const int q = qb + j;         // 0..7, local d = q*4
                    const float4 v = *(const float4*)(crow + q * 4);
                    cs[(q * 4 + 0) * BN + k] = v.x;
                    cs[(q * 4 + 1) * BN + k] = v.y;
                    cs[(q * 4 + 2) * BN + k] = v.z;
                    cs[(q * 4 + 3) * BN + k] = v.w;
                }
            }
            __syncthreads();
#pragma unroll
            for (int d = 0; d < DCH; ++d) {
                const float4 xa = *(const float4*)&xs[(dc * DCH + d) * BM + tr * 4];
                const float4 ca = *(const float4*)&cs[d * BN + tc * 4];
                const float4 cb2 = *(const float4*)&cs[d * BN + 64 + tc * 4];
                const float xv[4] = {xa.x, xa.y, xa.z, xa.w};
                const float cv[8] = {ca.x, ca.y, ca.z, ca.w, cb2.x, cb2.y, cb2.z, cb2.w};
#pragma unroll
                for (int i = 0; i < 4; ++i)
#pragma unroll
                    for (int j = 0; j < 8; ++j)
                        acc[i][j] = fmaf(xv[i], cv[j], acc[i][j]);
            }
        }

        // ---- tile epilogue: dist + running argmin (ascending code order) ----
        float csq_r[8];
#pragma unroll
        for (int j = 0; j < 4; ++j) {
            csq_r[j]     = csq[ct * BN + tc * 4 + j];
            csq_r[4 + j] = csq[ct * BN + 64 + tc * 4 + j];
        }
#pragma unroll
        for (int i = 0; i < 4; ++i) {
#pragma unroll
            for (int j = 0; j < 8; ++j) {
                const int cj = ct * BN + ((j < 4) ? (tc * 4 + j) : (64 + tc * 4 + j - 4));
                const float dist = fmaf(-2.0f, acc[i][j], xsq[i]) + csq_r[j];
                if (dist < best[i]) { best[i] = dist; bidx[i] = cj; }
            }
        }
    }

    // ---- cross-thread per-row argmin reduction (value, then index) ----
    __syncthreads();              // all compute done; reuse cs
    float* redb = cs;             // [64][16] best
    int* redi = (int*)cs + BM * 16;  // [64][16] idx
#pragma unroll
    for (int i = 0; i < 4; ++i) {
        const int r = tr * 4 + i;
        redb[r * 16 + tc] = best[i];
        redi[r * 16 + tc] = bidx[i];
    }
    __syncthreads();
    if (tid < BM) {
        float b = redb[tid * 16];
        int bi = redi[tid * 16];
#pragma unroll
        for (int e = 1; e < 16; ++e) {
            const float v = redb[tid * 16 + e];
            const int vi = redi[tid * 16 + e];
            if (v < b || (v == b && vi < bi)) { b = v; bi = vi; }
        }
        codes[r0 + tid] = (float)bi;
        win[tid] = bi;
    }
    __syncthreads();

    // ---- gather winner rows ----
    {
        const int r = tid >> 2;
        const int qb = (tid & 3) * 8;
        const float* __restrict__ crow = cb + (long)win[r] * DDIM;
        float* __restrict__ qrow = quant + (r0 + r) * DDIM;
#pragma unroll
        for (int j = 0; j < 8; ++j) {
            const int q = qb + j;
            *(float4*)(qrow + q * 4) = *(const float4*)(crow + q * 4);
        }
    }
}

extern "C" void kernel_launch(void* const* d_in, const int* in_sizes, int n_in,
                              void* d_out, int out_size, void* d_ws, size_t ws_size,
                              hipStream_t stream) {
    const float* x  = (const float*)d_in[0];
    const float* cb = (const float*)d_in[1];
    const int B = in_sizes[0] / DDIM;  // 200000

    float* quant = (float*)d_out;
    float* codes = (float*)d_out + (size_t)B * DDIM;
    float* csq   = (float*)d_ws;

    csq_kernel<<<(KCODES + 255) / 256, 256, 0, stream>>>(cb, csq);

    const int blocks = B / BM;  // 3125 exact
    vq_gemm_kernel<<<blocks, 256, 0, stream>>>(x, cb, csq, quant, codes);
}

// Round 4
// 831.517 us; speedup vs baseline: 3.1127x; 1.2326x over previous
//
#include <hip/hip_runtime.h>

// VQ: B=200000 rows (D=128 fp32) vs K=1024 codes; out = [quant B*D | codes B] fp32.
//
// R2 lessons: (1) pointer-select among allocas in x_sq defeated SROA -> 450 MB
// of scratch RMW traffic (WRITE 548 MB vs 103 MB output) + ~317 us of extra
// VALU. (2) scalar v_fma_f32 floors at 333 us; v_pk_fma_f32 (VOP3P) halves
// issue slots -> use <2 x float> elementwise fma.
// Numerics: each acc element keeps the exact serial-over-d fma chain of R2
// (absmax was 0.0), so distances are bit-identical.

typedef float v2f __attribute__((ext_vector_type(2)));

#define DDIM 128
#define KCODES 1024
#define BM 64              // rows per block (200000 = 3125 * 64, exact)
#define BN 128             // codes per tile
#define DCH 32             // d-chunk
#define NTILES (KCODES / BN)
#define NCHUNK (DDIM / DCH)

__global__ void csq_kernel(const float* __restrict__ cb, float* __restrict__ csq) {
    int k = blockIdx.x * blockDim.x + threadIdx.x;
    if (k >= KCODES) return;
    const float* __restrict__ c = cb + (long)k * DDIM;
    float s0 = 0.f, s1 = 0.f, s2 = 0.f, s3 = 0.f;
#pragma unroll
    for (int d = 0; d < DDIM; d += 4) {
        s0 = fmaf(c[d + 0], c[d + 0], s0);
        s1 = fmaf(c[d + 1], c[d + 1], s1);
        s2 = fmaf(c[d + 2], c[d + 2], s2);
        s3 = fmaf(c[d + 3], c[d + 3], s3);
    }
    csq[k] = (s0 + s1) + (s2 + s3);
}

__launch_bounds__(256, 3)  // VGPR cap ~170; LDS 48.5KB -> 3 blocks/CU
__global__ void vq_gemm_kernel(const float* __restrict__ x, const float* __restrict__ cb,
                               const float* __restrict__ csq, float* __restrict__ quant,
                               float* __restrict__ codes) {
    __shared__ float xs[DDIM * BM];   // [d][r] transposed, 32 KB, staged once
    __shared__ float cs[DCH * BN];    // [d][k] transposed, 16 KB (reused for reduction)
    __shared__ int win[BM];

    const int tid = threadIdx.x;
    const long r0 = (long)blockIdx.x * BM;

    // ---- stage x tile (64 rows x 128 d), transposed into xs[d][r] ----
    {
        const int r = tid >> 2;            // 0..63
        const int qb = (tid & 3) * 8;      // quad base
        const float* __restrict__ xrow = x + (r0 + r) * DDIM;
#pragma unroll
        for (int j = 0; j < 8; ++j) {
            const int q = qb + j;          // quad 0..31, d = q*4
            const float4 v = *(const float4*)(xrow + q * 4);
            xs[(q * 4 + 0) * BM + r] = v.x;
            xs[(q * 4 + 1) * BM + r] = v.y;
            xs[(q * 4 + 2) * BM + r] = v.z;
            xs[(q * 4 + 3) * BM + r] = v.w;
        }
    }
    __syncthreads();

    const int tr = tid >> 4;   // 0..15 -> rows tr*4..+3
    const int tc = tid & 15;   // 0..15 -> codes {tc*4..+3} u {64+tc*4..+3}

    // ---- x_sq per row: 4 chains (d mod 4), constant indices only (no pointer
    // select -> SROA keeps s[][] in VGPRs; R2's version leaked to scratch) ----
    float s[4][4];
#pragma unroll
    for (int a = 0; a < 4; ++a)
#pragma unroll
        for (int b = 0; b < 4; ++b) s[a][b] = 0.f;
#pragma unroll
    for (int d = 0; d < DDIM; d += 4) {
#pragma unroll
        for (int dd = 0; dd < 4; ++dd) {
            const float4 v = *(const float4*)&xs[(d + dd) * BM + tr * 4];
            s[dd][0] = fmaf(v.x, v.x, s[dd][0]);
            s[dd][1] = fmaf(v.y, v.y, s[dd][1]);
            s[dd][2] = fmaf(v.z, v.z, s[dd][2]);
            s[dd][3] = fmaf(v.w, v.w, s[dd][3]);
        }
    }
    float xsq[4];
#pragma unroll
    for (int i = 0; i < 4; ++i) xsq[i] = (s[0][i] + s[1][i]) + (s[2][i] + s[3][i]);

    float best[4];
    int bidx[4];
#pragma unroll
    for (int i = 0; i < 4; ++i) { best[i] = 3.4e38f; bidx[i] = 0; }

    for (int ct = 0; ct < NTILES; ++ct) {
        v2f acc[4][4];   // [row i][code-pair jj]; jj<2 -> codes tc*4+{2jj,2jj+1}, jj>=2 -> 64+...
#pragma unroll
        for (int i = 0; i < 4; ++i)
#pragma unroll
            for (int jj = 0; jj < 4; ++jj) acc[i][jj] = (v2f){0.f, 0.f};

        for (int dc = 0; dc < NCHUNK; ++dc) {
            __syncthreads();  // protect cs from previous tile/chunk readers
            {   // stage codebook chunk: codes ct*BN+(0..127), dims dc*32..+31
                const int k = tid >> 1;           // 0..127
                const int qb = (tid & 1) * 4;     // 0 or 4
                const float* __restrict__ crow =
                    cb + (long)(ct * BN + k) * DDIM + dc * DCH;
#pragma unroll
                for (int j = 0; j < 4; ++j) {
                    const int q = qb + j;         // 0..7, local d = q*4
                    const float4 v = *(const float4*)(crow + q * 4);
                    cs[(q * 4 + 0) * BN + k] = v.x;
                    cs[(q * 4 + 1) * BN + k] = v.y;
                    cs[(q * 4 + 2) * BN + k] = v.z;
                    cs[(q * 4 + 3) * BN + k] = v.w;
                }
            }
            __syncthreads();
#pragma unroll
            for (int d = 0; d < DCH; ++d) {
                const float4 xa  = *(const float4*)&xs[(dc * DCH + d) * BM + tr * 4];
                const float4 ca  = *(const float4*)&cs[d * BN + tc * 4];
                const float4 cb2 = *(const float4*)&cs[d * BN + 64 + tc * 4];
                const float xv[4] = {xa.x, xa.y, xa.z, xa.w};
                v2f cv[4];
                cv[0] = (v2f){ca.x, ca.y};
                cv[1] = (v2f){ca.z, ca.w};
                cv[2] = (v2f){cb2.x, cb2.y};
                cv[3] = (v2f){cb2.z, cb2.w};
#pragma unroll
                for (int i = 0; i < 4; ++i) {
                    const v2f xb = (v2f){xv[i], xv[i]};
#pragma unroll
                    for (int jj = 0; jj < 4; ++jj)
                        acc[i][jj] = __builtin_elementwise_fma(xb, cv[jj], acc[i][jj]);
                }
            }
        }

        // ---- tile epilogue: dist + running argmin (ascending code order) ----
        float csq_r[8];
#pragma unroll
        for (int j = 0; j < 4; ++j) {
            csq_r[j]     = csq[ct * BN + tc * 4 + j];
            csq_r[4 + j] = csq[ct * BN + 64 + tc * 4 + j];
        }
#pragma unroll
        for (int i = 0; i < 4; ++i) {
#pragma unroll
            for (int jj = 0; jj < 4; ++jj) {
#pragma unroll
                for (int h = 0; h < 2; ++h) {
                    const int jl = jj * 2 + h;  // 0..7, ascending
                    const int cj = ct * BN + ((jl < 4) ? (tc * 4 + jl) : (64 + tc * 4 + jl - 4));
                    const float dist = fmaf(-2.0f, acc[i][jj][h], xsq[i]) + csq_r[jl];
                    if (dist < best[i]) { best[i] = dist; bidx[i] = cj; }
                }
            }
        }
    }

    // ---- cross-thread per-row argmin reduction (value, then index) ----
    __syncthreads();              // all compute done; reuse cs
    float* redb = cs;             // [64][16] best
    int* redi = (int*)cs + BM * 16;  // [64][16] idx
#pragma unroll
    for (int i = 0; i < 4; ++i) {
        const int r = tr * 4 + i;
        redb[r * 16 + tc] = best[i];
        redi[r * 16 + tc] = bidx[i];
    }
    __syncthreads();
    if (tid < BM) {
        float b = redb[tid * 16];
        int bi = redi[tid * 16];
#pragma unroll
        for (int e = 1; e < 16; ++e) {
            const float v = redb[tid * 16 + e];
            const int vi = redi[tid * 16 + e];
            if (v < b || (v == b && vi < bi)) { b = v; bi = vi; }
        }
        codes[r0 + tid] = (float)bi;
        win[tid] = bi;
    }
    __syncthreads();

    // ---- gather winner rows ----
    {
        const int r = tid >> 2;
        const int qb = (tid & 3) * 8;
        const float* __restrict__ crow = cb + (long)win[r] * DDIM;
        float* __restrict__ qrow = quant + (r0 + r) * DDIM;
#pragma unroll
        for (int j = 0; j < 8; ++j) {
            const int q = qb + j;
            *(float4*)(qrow + q * 4) = *(const float4*)(crow + q * 4);
        }
    }
}

extern "C" void kernel_launch(void* const* d_in, const int* in_sizes, int n_in,
                              void* d_out, int out_size, void* d_ws, size_t ws_size,
                              hipStream_t stream) {
    const float* x  = (const float*)d_in[0];
    const float* cb = (const float*)d_in[1];
    const int B = in_sizes[0] / DDIM;  // 200000

    float* quant = (float*)d_out;
    float* codes = (float*)d_out + (size_t)B * DDIM;
    float* csq   = (float*)d_ws;

    csq_kernel<<<(KCODES + 255) / 256, 256, 0, stream>>>(cb, csq);

    const int blocks = B / BM;  // 3125 exact
    vq_gemm_kernel<<<blocks, 256, 0, stream>>>(x, cb, csq, quant, codes);
}